// Round 5
// baseline (784.051 us; speedup 1.0000x reference)
//
#include <hip/hip_runtime.h>
#include <stdint.h>

#define D_MODEL 2048
#define SEQ     2048
#define BATCH   2
#define NHEAD   16
#define HD      128
#define MROWS   (BATCH*SEQ)   // 4096

typedef short short8 __attribute__((ext_vector_type(8)));
typedef float f32x4  __attribute__((ext_vector_type(4)));

__device__ __forceinline__ unsigned short f2b(float f) {
  unsigned int u = __float_as_uint(f);
  u += 0x7fffu + ((u >> 16) & 1u);          // RNE
  return (unsigned short)(u >> 16);
}
__device__ __forceinline__ float b2f(unsigned short s) {
  return __uint_as_float(((unsigned int)s) << 16);
}
__device__ __forceinline__ void gll16(const void* g, void* l) {
  __builtin_amdgcn_global_load_lds((const __attribute__((address_space(1))) void*)g,
                                   (__attribute__((address_space(3))) void*)l, 16, 0, 0);
}

// ---------------- cast fp32 -> bf16 (x | Wq | Wk | Wv | Wo contiguous) ----------------
__global__ __launch_bounds__(256) void cast_all(
    const float* __restrict__ x,  const float* __restrict__ Wq,
    const float* __restrict__ Wk, const float* __restrict__ Wv,
    const float* __restrict__ Wo, unsigned short* __restrict__ dst)
{
  size_t e = ((size_t)blockIdx.x * 256 + threadIdx.x) * 4;
  const size_t XN = (size_t)MROWS * D_MODEL;   // 2^23
  const size_t WN = (size_t)D_MODEL * D_MODEL; // 2^22
  const float* src; size_t off;
  if (e < XN) { src = x; off = e; }
  else {
    size_t e2 = e - XN;
    int w = (int)(e2 >> 22);
    off = e2 & (WN - 1);
    src = (w == 0) ? Wq : (w == 1) ? Wk : (w == 2) ? Wv : Wo;
  }
  float4 v = *(const float4*)(src + off);
  ushort4 o;
  o.x = f2b(v.x); o.y = f2b(v.y); o.z = f2b(v.z); o.w = f2b(v.w);
  *(ushort4*)(dst + e) = o;
}

// ---------------- 128x128 bf16 GEMM core: C = A @ B^T ----------------
// LDS chunk xor-swizzle (chunk' = chunk ^ ((row>>1)&3)) breaks the 8-way
// bank conflict of the linear layout (row stride 64B => 2 bank-groups/quad).
__device__ __forceinline__ void gemm_core(
    const unsigned short* __restrict__ A, const unsigned short* __restrict__ Bw,
    unsigned short* As, unsigned short* Bs, int m0, int n0, int tid,
    f32x4 (&acc)[4][4])
{
  const int K = D_MODEL;
  const int wave = tid >> 6, lane = tid & 63, l15 = lane & 15, quad = lane >> 4;
  const int wr = wave >> 1, wc = wave & 1;

  for (int kt = 0; kt < K; kt += 32) {
    #pragma unroll
    for (int c = 0; c < 2; ++c) {
      int chunk = c * 256 + tid;
      int row = chunk >> 2, pch = chunk & 3;
      int sch = pch ^ ((row >> 1) & 3);        // swizzled source chunk
      const unsigned short* ga = A  + (size_t)(m0 + row) * K + kt + sch * 8;
      const unsigned short* gb = Bw + (size_t)(n0 + row) * K + kt + sch * 8;
      gll16(ga, As + (size_t)(c * 256 + wave * 64) * 8);
      gll16(gb, Bs + (size_t)(c * 256 + wave * 64) * 8);
    }
    __syncthreads();
    const int rch = quad ^ ((l15 >> 1) & 3);   // read-side swizzle (row bits from l15)
    short8 af[4], bfr[4];
    #pragma unroll
    for (int mi = 0; mi < 4; ++mi)
      af[mi] = *(const short8*)(As + (wr * 64 + mi * 16 + l15) * 32 + rch * 8);
    #pragma unroll
    for (int ni = 0; ni < 4; ++ni)
      bfr[ni] = *(const short8*)(Bs + (wc * 64 + ni * 16 + l15) * 32 + rch * 8);
    #pragma unroll
    for (int mi = 0; mi < 4; ++mi)
      #pragma unroll
      for (int ni = 0; ni < 4; ++ni)
        acc[mi][ni] = __builtin_amdgcn_mfma_f32_16x16x32_bf16(af[mi], bfr[ni], acc[mi][ni], 0, 0, 0);
    __syncthreads();
  }
}

__global__ __launch_bounds__(256) void gemm_qkv(
    const unsigned short* __restrict__ Axb,
    const unsigned short* __restrict__ Wq, const unsigned short* __restrict__ Wk,
    const unsigned short* __restrict__ Wv,
    unsigned short* __restrict__ Qh, unsigned short* __restrict__ Kh,
    unsigned short* __restrict__ Vt)
{
  __shared__ unsigned short As[128 * 32], Bs[128 * 32];
  const int z = blockIdx.z;
  const unsigned short* Bw = (z == 0) ? Wq : (z == 1) ? Wk : Wv;
  const int m0 = blockIdx.y * 128, n0 = blockIdx.x * 128;
  f32x4 acc[4][4];
  #pragma unroll
  for (int i = 0; i < 4; ++i)
    #pragma unroll
    for (int j = 0; j < 4; ++j) acc[i][j] = (f32x4){0.f, 0.f, 0.f, 0.f};
  gemm_core(Axb, Bw, As, Bs, m0, n0, threadIdx.x, acc);

  const int tid = threadIdx.x, wave = tid >> 6, lane = tid & 63;
  const int l15 = lane & 15, quad = lane >> 4, wr = wave >> 1, wc = wave & 1;
  if (z < 2) {
    unsigned short* dst = z ? Kh : Qh;
    #pragma unroll
    for (int mi = 0; mi < 4; ++mi)
      #pragma unroll
      for (int ni = 0; ni < 4; ++ni) {
        int row0 = m0 + wr * 64 + mi * 16 + quad * 4;
        int col  = n0 + wc * 64 + ni * 16 + l15;
        int h = col >> 7, d = col & (HD - 1);
        #pragma unroll
        for (int r = 0; r < 4; ++r) {
          int m = row0 + r; int bb = m >> 11; int s = m & (SEQ - 1);
          dst[((size_t)(bb * NHEAD + h) * SEQ + s) * HD + d] = f2b(acc[mi][ni][r]);
        }
      }
  } else {
    #pragma unroll
    for (int mi = 0; mi < 4; ++mi)
      #pragma unroll
      for (int ni = 0; ni < 4; ++ni) {
        int row0 = m0 + wr * 64 + mi * 16 + quad * 4;
        int col  = n0 + wc * 64 + ni * 16 + l15;
        int h = col >> 7, d = col & (HD - 1);
        int bb = row0 >> 11; int s = row0 & (SEQ - 1);
        ushort4 pk;
        pk.x = f2b(acc[mi][ni][0]); pk.y = f2b(acc[mi][ni][1]);
        pk.z = f2b(acc[mi][ni][2]); pk.w = f2b(acc[mi][ni][3]);
        *(ushort4*)(Vt + ((size_t)(bb * NHEAD + h) * HD + d) * SEQ + s) = pk;
      }
  }
}

__global__ __launch_bounds__(256) void gemm_out(
    const unsigned short* __restrict__ A, const unsigned short* __restrict__ Wo,
    float* __restrict__ C)
{
  __shared__ unsigned short As[128 * 32], Bs[128 * 32];
  const int m0 = blockIdx.y * 128, n0 = blockIdx.x * 128;
  f32x4 acc[4][4];
  #pragma unroll
  for (int i = 0; i < 4; ++i)
    #pragma unroll
    for (int j = 0; j < 4; ++j) acc[i][j] = (f32x4){0.f, 0.f, 0.f, 0.f};
  gemm_core(A, Wo, As, Bs, m0, n0, threadIdx.x, acc);

  const int tid = threadIdx.x, wave = tid >> 6, lane = tid & 63;
  const int l15 = lane & 15, quad = lane >> 4, wr = wave >> 1, wc = wave & 1;
  #pragma unroll
  for (int mi = 0; mi < 4; ++mi)
    #pragma unroll
    for (int ni = 0; ni < 4; ++ni) {
      int row0 = m0 + wr * 64 + mi * 16 + quad * 4;
      int col  = n0 + wc * 64 + ni * 16 + l15;
      #pragma unroll
      for (int r = 0; r < 4; ++r)
        C[(size_t)(row0 + r) * D_MODEL + col] = acc[mi][ni][r];
    }
}

// ---------------- RoPE in place on [b,h,s,d] bf16 ----------------
__global__ __launch_bounds__(256) void rope_k(unsigned short* __restrict__ Qh,
                                              unsigned short* __restrict__ Kh)
{
  unsigned short* P = blockIdx.y ? Kh : Qh;
  int rid = blockIdx.x * 4 + (threadIdx.x >> 6);
  int i = threadIdx.x & 63;
  int s = rid & (SEQ - 1);
  size_t base = (size_t)rid * HD + 2 * i;
  float inv = exp2f(-(float)i * (13.287712379549449f / 64.0f));
  float ang = (float)s * inv;
  float sn, cs; sincosf(ang, &sn, &cs);
  unsigned int pk = *(const unsigned int*)(P + base);
  float x1 = b2f((unsigned short)(pk & 0xffffu));
  float x2 = b2f((unsigned short)(pk >> 16));
  unsigned short o0 = f2b(x1 * cs - x2 * sn);
  unsigned short o1 = f2b(x1 * sn + x2 * cs);
  *(unsigned int*)(P + base) = (unsigned int)o0 | ((unsigned int)o1 << 16);
}

// ---------------- flash attention v5: barrier-free, direct-global operands ----------------
// One wave per 16 q-rows (4096 waves, all co-resident: 4 blocks/CU x 4 waves).
// K/V MFMA fragments are loaded straight from global (L1/L2-served, shared
// across co-resident waves); LDS holds only the per-wave P layout-transform
// buffer. No __syncthreads anywhere. Fragment math identical to verified v3:
// S^T = mfma(kf,qf) (row=k, col=q=l15), O^T = mfma(vf,pf) (row=d, col=q),
// so per-lane online-softmax state stays aligned.
__global__ __launch_bounds__(256) void attn_k(
    const unsigned short* __restrict__ Qh, const unsigned short* __restrict__ Kh,
    const unsigned short* __restrict__ Vt, unsigned short* __restrict__ Aout)
{
  __shared__ unsigned short sPb[4][16 * 88]; // per-wave P[q][k<64], stride 88 (2-way banks)
  const int tid = threadIdx.x;
  const int wave = tid >> 6, lane = tid & 63, l15 = lane & 15, quad = lane >> 4;
  const int bh = blockIdx.y;
  const int b = bh >> 4, h = bh & 15;
  const unsigned short* Qb = Qh + (size_t)bh * SEQ * HD;
  const unsigned short* Kb = Kh + (size_t)bh * SEQ * HD;
  const unsigned short* Vb = Vt + (size_t)bh * HD * SEQ;
  unsigned short* pw = &sPb[wave][0];
  const float scl = 0.08838834764831845f * 1.4426950408889634f; // 1/sqrt(128)*log2(e)

  const int t16 = 127 - (blockIdx.x * 4 + wave);  // heavy q-tiles first
  const int q0w = t16 * 16;
  const int q = q0w + l15;                        // this lane's q-row

  short8 qf[4];
  #pragma unroll
  for (int c = 0; c < 4; ++c)
    qf[c] = *(const short8*)(Qb + (size_t)q * HD + c * 32 + quad * 8);

  f32x4 o[8];                        // O^T: o[dj][r] = O[q][dj*16 + quad*4 + r]
  #pragma unroll
  for (int dj = 0; dj < 8; ++dj) o[dj] = (f32x4){0.f, 0.f, 0.f, 0.f};
  float ms = -1e30f, ls = 0.f;

  const int trips = (q0w >> 6) + 1;  // 64-wide k-tiles covering k <= q0w+15
  for (int it = 0; it < trips; ++it) {
    const int k0 = it * 64;

    // S^T = K_tile @ Q^T : fragments straight from global (row = k, col = q)
    f32x4 st[4];
    #pragma unroll
    for (int ni = 0; ni < 4; ++ni) st[ni] = (f32x4){0.f, 0.f, 0.f, 0.f};
    #pragma unroll
    for (int ni = 0; ni < 4; ++ni) {
      const unsigned short* krow = Kb + (size_t)(k0 + ni * 16 + l15) * HD;
      #pragma unroll
      for (int c = 0; c < 4; ++c) {
        short8 kf = *(const short8*)(krow + c * 32 + quad * 8);
        st[ni] = __builtin_amdgcn_mfma_f32_16x16x32_bf16(kf, qf[c], st[ni], 0, 0, 0);
      }
    }

    // causal mask (only near diagonal)
    if (k0 + 63 > q0w) {
      #pragma unroll
      for (int ni = 0; ni < 4; ++ni)
        #pragma unroll
        for (int r = 0; r < 4; ++r) {
          int k = k0 + ni * 16 + quad * 4 + r;
          if (k > q) st[ni][r] = -1e30f;
        }
    }

    // online softmax: per-lane (q-row l15) + 2 shuffles across quad partners
    float lm = -1e30f;
    #pragma unroll
    for (int ni = 0; ni < 4; ++ni)
      #pragma unroll
      for (int r = 0; r < 4; ++r) lm = fmaxf(lm, st[ni][r]);
    lm = fmaxf(lm, __shfl_xor(lm, 16, 64));
    lm = fmaxf(lm, __shfl_xor(lm, 32, 64));
    float mn = fmaxf(ms, lm);
    float al = exp2f((ms - mn) * scl);
    ms = mn;
    float nm = mn * scl;
    float rs = 0.f;
    #pragma unroll
    for (int ni = 0; ni < 4; ++ni)
      #pragma unroll
      for (int r = 0; r < 4; ++r) {
        float p = exp2f(fmaf(st[ni][r], scl, -nm));
        st[ni][r] = p;
        rs += p;
      }
    rs += __shfl_xor(rs, 16, 64);
    rs += __shfl_xor(rs, 32, 64);
    ls = ls * al + rs;
    #pragma unroll
    for (int dj = 0; dj < 8; ++dj) o[dj] *= al;   // O^T cols all q=l15: al aligned

    // P^T (st) -> wave-private LDS as P[q=l15][k], read back as B-operand
    #pragma unroll
    for (int ni = 0; ni < 4; ++ni) {
      ushort4 pk;
      pk.x = f2b(st[ni][0]); pk.y = f2b(st[ni][1]);
      pk.z = f2b(st[ni][2]); pk.w = f2b(st[ni][3]);
      *(ushort4*)(pw + l15 * 88 + ni * 16 + quad * 4) = pk;
    }
    short8 pf0 = *(const short8*)(pw + l15 * 88 + quad * 8);
    short8 pf1 = *(const short8*)(pw + l15 * 88 + 32 + quad * 8);

    // O^T += V^T_tile @ P^T : V fragments straight from global [d][s]
    #pragma unroll
    for (int dj = 0; dj < 8; ++dj) {
      const unsigned short* vrow = Vb + (size_t)(dj * 16 + l15) * SEQ + k0;
      short8 v0 = *(const short8*)(vrow + quad * 8);
      short8 v1 = *(const short8*)(vrow + 32 + quad * 8);
      o[dj] = __builtin_amdgcn_mfma_f32_16x16x32_bf16(v0, pf0, o[dj], 0, 0, 0);
      o[dj] = __builtin_amdgcn_mfma_f32_16x16x32_bf16(v1, pf1, o[dj], 0, 0, 0);
    }
  }

  // epilogue: o[dj][r] = O[q][d = dj*16 + quad*4 + r] (unnormalized)
  float rl = 1.0f / ls;
  #pragma unroll
  for (int dj = 0; dj < 8; ++dj) {
    ushort4 pk;
    pk.x = f2b(o[dj][0] * rl); pk.y = f2b(o[dj][1] * rl);
    pk.z = f2b(o[dj][2] * rl); pk.w = f2b(o[dj][3] * rl);
    *(ushort4*)(Aout + ((size_t)(b * SEQ + q)) * D_MODEL + h * HD + dj * 16 + quad * 4) = pk;
  }
}

extern "C" void kernel_launch(void* const* d_in, const int* in_sizes, int n_in,
                              void* d_out, int out_size, void* d_ws, size_t ws_size,
                              hipStream_t stream)
{
  const float* x  = (const float*)d_in[0];
  const float* Wq = (const float*)d_in[1];
  const float* Wk = (const float*)d_in[2];
  const float* Wv = (const float*)d_in[3];
  const float* Wo = (const float*)d_in[4];
  float* out = (float*)d_out;

  unsigned short* xb  = (unsigned short*)d_ws;        // 8M
  unsigned short* wqb = xb  + 8388608;                // 4M each
  unsigned short* wkb = wqb + 4194304;
  unsigned short* wvb = wkb + 4194304;
  unsigned short* wob = wvb + 4194304;
  unsigned short* qh  = wob + 4194304;                // 8M each
  unsigned short* kh  = qh  + 8388608;
  unsigned short* vt  = kh  + 8388608;
  unsigned short* ao  = vt  + 8388608;                // total 112 MB

  cast_all<<<24576, 256, 0, stream>>>(x, Wq, Wk, Wv, Wo, xb);
  gemm_qkv<<<dim3(16, 32, 3), 256, 0, stream>>>(xb, wqb, wkb, wvb, qh, kh, vt);
  rope_k<<<dim3(16384, 2), 256, 0, stream>>>(qh, kh);
  attn_k<<<dim3(32, 32), 256, 0, stream>>>(qh, kh, vt, ao);
  gemm_out<<<dim3(16, 32), 256, 0, stream>>>(ao, wob, out);
}

// Round 6
// 441.140 us; speedup vs baseline: 1.7773x; 1.7773x over previous
//
#include <hip/hip_runtime.h>
#include <stdint.h>

#define D_MODEL 2048
#define SEQ     2048
#define BATCH   2
#define NHEAD   16
#define HD      128
#define MROWS   (BATCH*SEQ)   // 4096

typedef short short8 __attribute__((ext_vector_type(8)));
typedef float f32x4  __attribute__((ext_vector_type(4)));

__device__ __forceinline__ unsigned short f2b(float f) {
  unsigned int u = __float_as_uint(f);
  u += 0x7fffu + ((u >> 16) & 1u);          // RNE
  return (unsigned short)(u >> 16);
}
__device__ __forceinline__ float b2f(unsigned short s) {
  return __uint_as_float(((unsigned int)s) << 16);
}
__device__ __forceinline__ void gll16(const void* g, void* l) {
  __builtin_amdgcn_global_load_lds((const __attribute__((address_space(1))) void*)g,
                                   (__attribute__((address_space(3))) void*)l, 16, 0, 0);
}

// ---------------- cast fp32 -> bf16 (x | Wq | Wk | Wv | Wo contiguous) ----------------
__global__ __launch_bounds__(256) void cast_all(
    const float* __restrict__ x,  const float* __restrict__ Wq,
    const float* __restrict__ Wk, const float* __restrict__ Wv,
    const float* __restrict__ Wo, unsigned short* __restrict__ dst)
{
  size_t e = ((size_t)blockIdx.x * 256 + threadIdx.x) * 4;
  const size_t XN = (size_t)MROWS * D_MODEL;   // 2^23
  const size_t WN = (size_t)D_MODEL * D_MODEL; // 2^22
  const float* src; size_t off;
  if (e < XN) { src = x; off = e; }
  else {
    size_t e2 = e - XN;
    int w = (int)(e2 >> 22);
    off = e2 & (WN - 1);
    src = (w == 0) ? Wq : (w == 1) ? Wk : (w == 2) ? Wv : Wo;
  }
  float4 v = *(const float4*)(src + off);
  ushort4 o;
  o.x = f2b(v.x); o.y = f2b(v.y); o.z = f2b(v.z); o.w = f2b(v.w);
  *(ushort4*)(dst + e) = o;
}

// ---------------- m97-style 128x128 bf16 GEMM core: C = A @ B^T ----------------
// (R3-exact: the R4 xor-swizzle regressed non-attn time 285->326 us; reverted)
__device__ __forceinline__ void gemm_core(
    const unsigned short* __restrict__ A, const unsigned short* __restrict__ Bw,
    unsigned short* As, unsigned short* Bs, int m0, int n0, int tid,
    f32x4 (&acc)[4][4])
{
  const int K = D_MODEL;
  const int wave = tid >> 6, lane = tid & 63, l15 = lane & 15, quad = lane >> 4;
  const int wr = wave >> 1, wc = wave & 1;

  for (int kt = 0; kt < K; kt += 32) {
    #pragma unroll
    for (int c = 0; c < 2; ++c) {
      int chunk = c * 256 + tid;
      const unsigned short* ga = A  + (size_t)(m0 + (chunk >> 2)) * K + kt + (chunk & 3) * 8;
      const unsigned short* gb = Bw + (size_t)(n0 + (chunk >> 2)) * K + kt + (chunk & 3) * 8;
      gll16(ga, As + (size_t)(c * 256 + wave * 64) * 8);
      gll16(gb, Bs + (size_t)(c * 256 + wave * 64) * 8);
    }
    __syncthreads();
    short8 af[4], bfr[4];
    #pragma unroll
    for (int mi = 0; mi < 4; ++mi)
      af[mi] = *(const short8*)(As + (wr * 64 + mi * 16 + l15) * 32 + quad * 8);
    #pragma unroll
    for (int ni = 0; ni < 4; ++ni)
      bfr[ni] = *(const short8*)(Bs + (wc * 64 + ni * 16 + l15) * 32 + quad * 8);
    #pragma unroll
    for (int mi = 0; mi < 4; ++mi)
      #pragma unroll
      for (int ni = 0; ni < 4; ++ni)
        acc[mi][ni] = __builtin_amdgcn_mfma_f32_16x16x32_bf16(af[mi], bfr[ni], acc[mi][ni], 0, 0, 0);
    __syncthreads();
  }
}

__global__ __launch_bounds__(256) void gemm_qkv(
    const unsigned short* __restrict__ Axb,
    const unsigned short* __restrict__ Wq, const unsigned short* __restrict__ Wk,
    const unsigned short* __restrict__ Wv,
    unsigned short* __restrict__ Qh, unsigned short* __restrict__ Kh,
    unsigned short* __restrict__ Vt)
{
  __shared__ unsigned short As[128 * 32], Bs[128 * 32];
  const int z = blockIdx.z;
  const unsigned short* Bw = (z == 0) ? Wq : (z == 1) ? Wk : Wv;
  const int m0 = blockIdx.y * 128, n0 = blockIdx.x * 128;
  f32x4 acc[4][4];
  #pragma unroll
  for (int i = 0; i < 4; ++i)
    #pragma unroll
    for (int j = 0; j < 4; ++j) acc[i][j] = (f32x4){0.f, 0.f, 0.f, 0.f};
  gemm_core(Axb, Bw, As, Bs, m0, n0, threadIdx.x, acc);

  const int tid = threadIdx.x, wave = tid >> 6, lane = tid & 63;
  const int l15 = lane & 15, quad = lane >> 4, wr = wave >> 1, wc = wave & 1;
  if (z < 2) {
    unsigned short* dst = z ? Kh : Qh;
    #pragma unroll
    for (int mi = 0; mi < 4; ++mi)
      #pragma unroll
      for (int ni = 0; ni < 4; ++ni) {
        int row0 = m0 + wr * 64 + mi * 16 + quad * 4;
        int col  = n0 + wc * 64 + ni * 16 + l15;
        int h = col >> 7, d = col & (HD - 1);
        #pragma unroll
        for (int r = 0; r < 4; ++r) {
          int m = row0 + r; int bb = m >> 11; int s = m & (SEQ - 1);
          dst[((size_t)(bb * NHEAD + h) * SEQ + s) * HD + d] = f2b(acc[mi][ni][r]);
        }
      }
  } else {
    #pragma unroll
    for (int mi = 0; mi < 4; ++mi)
      #pragma unroll
      for (int ni = 0; ni < 4; ++ni) {
        int row0 = m0 + wr * 64 + mi * 16 + quad * 4;
        int col  = n0 + wc * 64 + ni * 16 + l15;
        int h = col >> 7, d = col & (HD - 1);
        int bb = row0 >> 11; int s = row0 & (SEQ - 1);
        ushort4 pk;
        pk.x = f2b(acc[mi][ni][0]); pk.y = f2b(acc[mi][ni][1]);
        pk.z = f2b(acc[mi][ni][2]); pk.w = f2b(acc[mi][ni][3]);
        *(ushort4*)(Vt + ((size_t)(bb * NHEAD + h) * HD + d) * SEQ + s) = pk;
      }
  }
}

__global__ __launch_bounds__(256) void gemm_out(
    const unsigned short* __restrict__ A, const unsigned short* __restrict__ Wo,
    float* __restrict__ C)
{
  __shared__ unsigned short As[128 * 32], Bs[128 * 32];
  const int m0 = blockIdx.y * 128, n0 = blockIdx.x * 128;
  f32x4 acc[4][4];
  #pragma unroll
  for (int i = 0; i < 4; ++i)
    #pragma unroll
    for (int j = 0; j < 4; ++j) acc[i][j] = (f32x4){0.f, 0.f, 0.f, 0.f};
  gemm_core(A, Wo, As, Bs, m0, n0, threadIdx.x, acc);

  const int tid = threadIdx.x, wave = tid >> 6, lane = tid & 63;
  const int l15 = lane & 15, quad = lane >> 4, wr = wave >> 1, wc = wave & 1;
  #pragma unroll
  for (int mi = 0; mi < 4; ++mi)
    #pragma unroll
    for (int ni = 0; ni < 4; ++ni) {
      int row0 = m0 + wr * 64 + mi * 16 + quad * 4;
      int col  = n0 + wc * 64 + ni * 16 + l15;
      #pragma unroll
      for (int r = 0; r < 4; ++r)
        C[(size_t)(row0 + r) * D_MODEL + col] = acc[mi][ni][r];
    }
}

// ---------------- RoPE in place on [b,h,s,d] bf16 ----------------
__global__ __launch_bounds__(256) void rope_k(unsigned short* __restrict__ Qh,
                                              unsigned short* __restrict__ Kh)
{
  unsigned short* P = blockIdx.y ? Kh : Qh;
  int rid = blockIdx.x * 4 + (threadIdx.x >> 6);
  int i = threadIdx.x & 63;
  int s = rid & (SEQ - 1);
  size_t base = (size_t)rid * HD + 2 * i;
  float inv = exp2f(-(float)i * (13.287712379549449f / 64.0f));
  float ang = (float)s * inv;
  float sn, cs; sincosf(ang, &sn, &cs);
  unsigned int pk = *(const unsigned int*)(P + base);
  float x1 = b2f((unsigned short)(pk & 0xffffu));
  float x2 = b2f((unsigned short)(pk >> 16));
  unsigned short o0 = f2b(x1 * cs - x2 * sn);
  unsigned short o1 = f2b(x1 * sn + x2 * cs);
  *(unsigned int*)(P + base) = (unsigned int)o0 | ((unsigned int)o1 << 16);
}

// ---------------- flash attention v6: v3 + double-buffered K/V staging ----------------
// 64 q-rows/block (4 waves x 16), k-tile 64, paired q-tiles (t, 31-t) -> 33
// uniform trips/block. Double-buffer: ONE barrier per trip; prefetch for trip
// i+1 is issued AFTER the barrier and stays in flight during trip i's compute,
// so the vmcnt drain at the next barrier costs max(0, latency - compute) ~ 0.
__global__ __launch_bounds__(256) void attn_k(
    const unsigned short* __restrict__ Qh, const unsigned short* __restrict__ Kh,
    const unsigned short* __restrict__ Vt, unsigned short* __restrict__ Aout)
{
  __shared__ unsigned short Ks[2][64 * 128];  // 32 KB, chunk' = chunk ^ (row&15)
  __shared__ unsigned short Vs[2][128 * 64];  // 32 KB, chunk' = chunk ^ (row&7)
  __shared__ unsigned short sPb[4][16 * 72];  // 9 KB, per-wave P, stride 72
  const int tid = threadIdx.x;
  const int wave = tid >> 6, lane = tid & 63, l15 = lane & 15, quad = lane >> 4;
  const int bh = blockIdx.y;
  const int b = bh >> 4, h = bh & 15;
  const unsigned short* Qb = Qh + (size_t)bh * SEQ * HD;
  const unsigned short* Kb = Kh + (size_t)bh * SEQ * HD;
  const unsigned short* Vb = Vt + (size_t)bh * HD * SEQ;
  unsigned short* pw = &sPb[wave][0];
  const float scl = 0.08838834764831845f * 1.4426950408889634f; // 1/sqrt(128)*log2(e)

  // staging lanes (constant per thread)
  const int kslot_r = tid >> 4, kslot_c = tid & 15;   // K: 16 rows per 256-thread pass
  const int vslot_r = tid >> 3, vslot_c = tid & 7;    // V: 32 rows per pass

  #pragma unroll
  for (int half = 0; half < 2; ++half) {
    const int tile = half ? (31 - blockIdx.x) : blockIdx.x;
    const int q0w = tile * 64 + wave * 16;
    const int q = q0w + l15;          // this lane's q-row

    short8 qf[4];
    #pragma unroll
    for (int c = 0; c < 4; ++c)
      qf[c] = *(const short8*)(Qb + (size_t)q * HD + c * 32 + quad * 8);

    f32x4 o[8];
    #pragma unroll
    for (int dj = 0; dj < 8; ++dj) o[dj] = (f32x4){0.f, 0.f, 0.f, 0.f};
    float ms = -1e30f, ls = 0.f;

    const int trips = tile + 1;

    // guard buf0 against the previous half's last-trip readers, then prologue
    __syncthreads();
    #pragma unroll
    for (int c = 0; c < 4; ++c) {
      int slot = c * 256 + tid;
      int kr = kslot_r + c * 16;
      gll16(Kb + (size_t)kr * HD + ((kslot_c ^ (kr & 15)) * 8), &Ks[0][0] + slot * 8);
    }
    #pragma unroll
    for (int c = 0; c < 4; ++c) {
      int slot = c * 256 + tid;
      int vr = vslot_r + c * 32;
      gll16(Vb + (size_t)vr * SEQ + ((vslot_c ^ (vr & 7)) * 8), &Vs[0][0] + slot * 8);
    }

    for (int it = 0; it < trips; ++it) {
      const int k0 = it * 64;
      const int buf = it & 1;
      __syncthreads();   // drains the in-flight prefetch (issued ~1 compute ago)

      if (it + 1 < trips) {           // prefetch trip it+1 into the other buffer
        const int kn = k0 + 64;
        unsigned short* kd = &Ks[buf ^ 1][0];
        unsigned short* vd = &Vs[buf ^ 1][0];
        #pragma unroll
        for (int c = 0; c < 4; ++c) {
          int slot = c * 256 + tid;
          int kr = kslot_r + c * 16;
          gll16(Kb + (size_t)(kn + kr) * HD + ((kslot_c ^ (kr & 15)) * 8), kd + slot * 8);
        }
        #pragma unroll
        for (int c = 0; c < 4; ++c) {
          int slot = c * 256 + tid;
          int vr = vslot_r + c * 32;
          gll16(Vb + (size_t)vr * SEQ + kn + ((vslot_c ^ (vr & 7)) * 8), vd + slot * 8);
        }
      }

      const unsigned short* Kt = &Ks[buf][0];
      const unsigned short* Vtl = &Vs[buf][0];

      // S^T = K_tile @ Q^T : row = k (quad*4+r), col = q (l15)
      f32x4 st[4];
      #pragma unroll
      for (int ni = 0; ni < 4; ++ni) st[ni] = (f32x4){0.f, 0.f, 0.f, 0.f};
      #pragma unroll
      for (int ni = 0; ni < 4; ++ni) {
        const int rowb = (ni * 16 + l15) * 128;
        #pragma unroll
        for (int c = 0; c < 4; ++c) {
          short8 kf = *(const short8*)(Kt + rowb + (((c * 4 + quad) ^ l15) * 8));
          st[ni] = __builtin_amdgcn_mfma_f32_16x16x32_bf16(kf, qf[c], st[ni], 0, 0, 0);
        }
      }

      // causal mask (only near diagonal)
      if (k0 + 63 > q0w) {
        #pragma unroll
        for (int ni = 0; ni < 4; ++ni)
          #pragma unroll
          for (int r = 0; r < 4; ++r) {
            int k = k0 + ni * 16 + quad * 4 + r;
            if (k > q) st[ni][r] = -1e30f;
          }
      }

      // online softmax: per-lane (q-row l15) + 2 shuffles across quad partners
      float lm = -1e30f;
      #pragma unroll
      for (int ni = 0; ni < 4; ++ni)
        #pragma unroll
        for (int r = 0; r < 4; ++r) lm = fmaxf(lm, st[ni][r]);
      lm = fmaxf(lm, __shfl_xor(lm, 16, 64));
      lm = fmaxf(lm, __shfl_xor(lm, 32, 64));
      float mn = fmaxf(ms, lm);
      float al = exp2f((ms - mn) * scl);
      ms = mn;
      float nm = mn * scl;
      float rs = 0.f;
      #pragma unroll
      for (int ni = 0; ni < 4; ++ni)
        #pragma unroll
        for (int r = 0; r < 4; ++r) {
          float p = exp2f(fmaf(st[ni][r], scl, -nm));
          st[ni][r] = p;
          rs += p;
        }
      rs += __shfl_xor(rs, 16, 64);
      rs += __shfl_xor(rs, 32, 64);
      ls = ls * al + rs;
      #pragma unroll
      for (int dj = 0; dj < 8; ++dj) o[dj] *= al;   // O^T cols all q=l15: aligned

      // P^T (st) -> wave-private LDS as P[q=l15][k], read back as B-operand
      #pragma unroll
      for (int ni = 0; ni < 4; ++ni) {
        ushort4 pk;
        pk.x = f2b(st[ni][0]); pk.y = f2b(st[ni][1]);
        pk.z = f2b(st[ni][2]); pk.w = f2b(st[ni][3]);
        *(ushort4*)(pw + l15 * 72 + ni * 16 + quad * 4) = pk;
      }
      short8 pf0 = *(const short8*)(pw + l15 * 72 + quad * 8);
      short8 pf1 = *(const short8*)(pw + l15 * 72 + 32 + quad * 8);

      // O^T += V^T_tile @ P^T : mfma(A=vf, B=pf) -> D[m=d-offset][n=q]
      #pragma unroll
      for (int dj = 0; dj < 8; ++dj) {
        const int vrow = (dj * 16 + l15) * 64;
        short8 v0 = *(const short8*)(Vtl + vrow + (((quad) ^ (l15 & 7)) * 8));
        short8 v1 = *(const short8*)(Vtl + vrow + (((4 + quad) ^ (l15 & 7)) * 8));
        o[dj] = __builtin_amdgcn_mfma_f32_16x16x32_bf16(v0, pf0, o[dj], 0, 0, 0);
        o[dj] = __builtin_amdgcn_mfma_f32_16x16x32_bf16(v1, pf1, o[dj], 0, 0, 0);
      }
    }

    // epilogue: o[dj][r] = O[q = q0w+l15][d = dj*16 + quad*4 + r] (unnormalized)
    float rl = 1.0f / ls;
    #pragma unroll
    for (int dj = 0; dj < 8; ++dj) {
      ushort4 pk;
      pk.x = f2b(o[dj][0] * rl); pk.y = f2b(o[dj][1] * rl);
      pk.z = f2b(o[dj][2] * rl); pk.w = f2b(o[dj][3] * rl);
      *(ushort4*)(Aout + ((size_t)(b * SEQ + q)) * D_MODEL + h * HD + dj * 16 + quad * 4) = pk;
    }
  }
}

extern "C" void kernel_launch(void* const* d_in, const int* in_sizes, int n_in,
                              void* d_out, int out_size, void* d_ws, size_t ws_size,
                              hipStream_t stream)
{
  const float* x  = (const float*)d_in[0];
  const float* Wq = (const float*)d_in[1];
  const float* Wk = (const float*)d_in[2];
  const float* Wv = (const float*)d_in[3];
  const float* Wo = (const float*)d_in[4];
  float* out = (float*)d_out;

  unsigned short* xb  = (unsigned short*)d_ws;        // 8M
  unsigned short* wqb = xb  + 8388608;                // 4M each
  unsigned short* wkb = wqb + 4194304;
  unsigned short* wvb = wkb + 4194304;
  unsigned short* wob = wvb + 4194304;
  unsigned short* qh  = wob + 4194304;                // 8M each
  unsigned short* kh  = qh  + 8388608;
  unsigned short* vt  = kh  + 8388608;
  unsigned short* ao  = vt  + 8388608;                // total 112 MB

  cast_all<<<24576, 256, 0, stream>>>(x, Wq, Wk, Wv, Wo, xb);
  gemm_qkv<<<dim3(16, 32, 3), 256, 0, stream>>>(xb, wqb, wkb, wvb, qh, kh, vt);
  rope_k<<<dim3(16384, 2), 256, 0, stream>>>(qh, kh);
  attn_k<<<dim3(16, 32), 256, 0, stream>>>(qh, kh, vt, ao);
  gemm_out<<<dim3(16, 32), 256, 0, stream>>>(ao, wob, out);
}